// Round 1
// baseline (2108.982 us; speedup 1.0000x reference)
//
#include <hip/hip_runtime.h>
#include <math.h>

#define NB 8
#define NC 96
#define NC2 192
#define NHH 128
#define NWW 128
#define NSP 16384
#define NHEADS 6

#define FMA4(A, S, V) { (A).x += (S)*(V).x; (A).y += (S)*(V).y; (A).z += (S)*(V).z; (A).w += (S)*(V).w; }

// ---------------- conv 1x1: out[b,oc,n] = sum_ic w[oc*96+ic] * in[b,ic,n]; Cout=192, Cin=96
// block: 16 oc x 1024 n, thread: 16 oc x 4 px (acc = float4 over pixels)
__global__ __launch_bounds__(256)
void conv1x1_k(const float* __restrict__ in, const float* __restrict__ w,
               float* __restrict__ out) {
  __shared__ float4 x_s[8 * 256];
  __shared__ float  w_s[8 * 16];
  const int tid = threadIdx.x;
  const int n0  = blockIdx.x * 1024;
  const int oc0 = blockIdx.y * 16;
  const int b   = blockIdx.z;
  float4 acc[16];
#pragma unroll
  for (int j = 0; j < 16; ++j) acc[j] = make_float4(0.f, 0.f, 0.f, 0.f);
  for (int ic0 = 0; ic0 < 96; ic0 += 8) {
    __syncthreads();
    const float* bp = in + ((size_t)b * NC + ic0) * NSP + n0;
#pragma unroll
    for (int it = 0; it < 8; ++it) {
      int i = it * 256 + tid;
      int icl = i >> 8, c4 = i & 255;
      x_s[i] = *(const float4*)(bp + (size_t)icl * NSP + (c4 << 2));
    }
    if (tid < 128) {
      int icl = tid >> 4, oc = tid & 15;
      w_s[icl * 16 + oc] = w[(oc0 + oc) * 96 + ic0 + icl];
    }
    __syncthreads();
#pragma unroll
    for (int icl = 0; icl < 8; ++icl) {
      float4 xv = x_s[icl * 256 + tid];
      const float4* wp = (const float4*)&w_s[icl * 16];
#pragma unroll
      for (int g = 0; g < 4; ++g) {
        float4 wv = wp[g];
        FMA4(acc[g*4+0], wv.x, xv);
        FMA4(acc[g*4+1], wv.y, xv);
        FMA4(acc[g*4+2], wv.z, xv);
        FMA4(acc[g*4+3], wv.w, xv);
      }
    }
  }
  float* op = out + ((size_t)b * NC2 + oc0) * NSP + n0 + (tid << 2);
#pragma unroll
  for (int j = 0; j < 16; ++j)
    *(float4*)(op + (size_t)j * NSP) = acc[j];
}

// ---------------- depthwise 3x3, pad 1, 192 channels
__global__ __launch_bounds__(256)
void dw3x3_k(const float* __restrict__ in, const float* __restrict__ wdw,
             float* __restrict__ out) {
  int n = blockIdx.x * 256 + threadIdx.x;
  int c = blockIdx.y, b = blockIdx.z;
  int pw = n & 127, ph = n >> 7;
  const float* ip = in + ((size_t)b * NC2 + c) * NSP;
  const float* wp = wdw + c * 9;
  float acc = 0.f;
#pragma unroll
  for (int ky = 0; ky < 3; ++ky) {
    int hh = ph + ky - 1;
    if ((unsigned)hh >= 128u) continue;
#pragma unroll
    for (int kx = 0; kx < 3; ++kx) {
      int ww2 = pw + kx - 1;
      if ((unsigned)ww2 < 128u) acc += wp[ky * 3 + kx] * ip[hh * NWW + ww2];
    }
  }
  out[((size_t)b * NC2 + c) * NSP + n] = acc;
}

// ---------------- v = conv3x3(concat[v0 (kv ch 96..191), v_ (qv ch 96..191)], w_fuse) + b_fuse
// block: 32x32 spatial tile, 16 oc; thread: 16 oc x 4 px
__global__ __launch_bounds__(256)
void fuse3x3_k(const float* __restrict__ qv, const float* __restrict__ kv,
               const float* __restrict__ wf, const float* __restrict__ bf,
               float* __restrict__ vout) {
  __shared__ float tile[4][34 * 36];
  __shared__ float w_s[4][9][16];
  const int tid = threadIdx.x;
  const int th0 = (blockIdx.x >> 2) * 32, tw0 = (blockIdx.x & 3) * 32;
  const int oc0 = blockIdx.y * 16, b = blockIdx.z;
  const int row = tid >> 3, col = (tid & 7) << 2;
  float4 acc[16];
#pragma unroll
  for (int j = 0; j < 16; ++j) { float bv = bf[oc0 + j]; acc[j] = make_float4(bv, bv, bv, bv); }
  for (int ic0 = 0; ic0 < 192; ic0 += 4) {
    __syncthreads();
    for (int i = tid; i < 4 * 1156; i += 256) {
      int icl = i / 1156, rem = i - icl * 1156;
      int r = rem / 34, cc = rem - r * 34;
      int ic = ic0 + icl;
      const float* src = (ic < 96) ? (kv + ((size_t)b * NC2 + 96 + ic) * NSP)
                                   : (qv + ((size_t)b * NC2 + ic) * NSP);
      int gh = th0 - 1 + r, gw = tw0 - 1 + cc;
      float vv = 0.f;
      if ((unsigned)gh < 128u && (unsigned)gw < 128u) vv = src[gh * NWW + gw];
      tile[icl][r * 36 + cc] = vv;
    }
    for (int i = tid; i < 4 * 144; i += 256) {
      int icl = i / 144, rem = i - icl * 144;
      int k = rem >> 4, oc = rem & 15;
      w_s[icl][k][oc] = wf[(size_t)(oc0 + oc) * 1728 + (ic0 + icl) * 9 + k];
    }
    __syncthreads();
#pragma unroll
    for (int icl = 0; icl < 4; ++icl) {
#pragma unroll
      for (int ky = 0; ky < 3; ++ky) {
#pragma unroll
        for (int kx = 0; kx < 3; ++kx) {
          const float* tp = &tile[icl][(row + ky) * 36 + col + kx];
          float4 tv = make_float4(tp[0], tp[1], tp[2], tp[3]);
          const float4* wp = (const float4*)&w_s[icl][ky * 3 + kx][0];
#pragma unroll
          for (int g = 0; g < 4; ++g) {
            float4 wv = wp[g];
            FMA4(acc[g*4+0], wv.x, tv);
            FMA4(acc[g*4+1], wv.y, tv);
            FMA4(acc[g*4+2], wv.z, tv);
            FMA4(acc[g*4+3], wv.w, tv);
          }
        }
      }
    }
  }
  float* op = vout + ((size_t)b * NC + oc0) * NSP + (th0 + row) * NWW + tw0 + col;
#pragma unroll
  for (int j = 0; j < 16; ++j)
    *(float4*)(op + (size_t)j * NSP) = acc[j];
}

// ---------------- per-row L2 norm over spatial dim; inv[z*768 + b*96 + c]
__global__ __launch_bounds__(256)
void rownorm_k(const float* __restrict__ qv, const float* __restrict__ kv,
               float* __restrict__ inv) {
  int c = blockIdx.x, b = blockIdx.y, z = blockIdx.z;
  const float4* p = (const float4*)((z ? kv : qv) + ((size_t)b * NC2 + c) * NSP);
  float ss = 0.f;
  for (int i = threadIdx.x; i < 4096; i += 256) {
    float4 v4 = p[i];
    ss += v4.x * v4.x + v4.y * v4.y + v4.z * v4.z + v4.w * v4.w;
  }
#pragma unroll
  for (int off = 32; off > 0; off >>= 1) ss += __shfl_down(ss, off);
  __shared__ float red[4];
  if ((threadIdx.x & 63) == 0) red[threadIdx.x >> 6] = ss;
  __syncthreads();
  if (threadIdx.x == 0) {
    float tot = red[0] + red[1] + red[2] + red[3];
    inv[z * NB * NC + b * NC + c] = 1.f / fmaxf(sqrtf(tot), 1e-12f);
  }
}

// ---------------- QK^T partials: logits[b,h,c,d] += dot over n-slice of 512
__global__ __launch_bounds__(256)
void qk_k(const float* __restrict__ qv, const float* __restrict__ kv,
          float* __restrict__ logits) {
  int slice = blockIdx.x, h = blockIdx.y, b = blockIdx.z;
  int c = threadIdx.x >> 4, d = threadIdx.x & 15;
  const float4* qp = (const float4*)(qv + ((size_t)b * NC2 + h * 16 + c) * NSP + slice * 512);
  const float4* kp = (const float4*)(kv + ((size_t)b * NC2 + h * 16 + d) * NSP + slice * 512);
  float acc = 0.f;
#pragma unroll 4
  for (int j = 0; j < 128; ++j) {
    float4 a = qp[j], e = kp[j];
    acc += a.x * e.x + a.y * e.y + a.z * e.z + a.w * e.w;
  }
  atomicAdd(&logits[((b * NHEADS + h) * 16 + c) * 16 + d], acc);
}

// ---------------- scale by inv norms * temperature, softmax over d
__global__ __launch_bounds__(256)
void softmax_k(const float* __restrict__ logits, const float* __restrict__ inv,
               const float* __restrict__ temp, float* __restrict__ attn) {
  int t = blockIdx.x * 256 + threadIdx.x;
  if (t >= NB * NC) return;
  int b = t / NC, c96 = t - b * NC;
  int h = c96 >> 4, c = c96 & 15;
  float iq = inv[b * NC + c96];
  float tp = temp[h];
  const float* lp  = logits + ((b * NHEADS + h) * 16 + c) * 16;
  const float* ikp = inv + NB * NC + b * NC + h * 16;
  float s[16], mx = -3.4e38f;
#pragma unroll
  for (int d = 0; d < 16; ++d) {
    float l = lp[d] * iq * ikp[d] * tp;
    s[d] = l; mx = fmaxf(mx, l);
  }
  float sum = 0.f;
#pragma unroll
  for (int d = 0; d < 16; ++d) { s[d] = expf(s[d] - mx); sum += s[d]; }
  float r = 1.f / sum;
  float* ap = attn + ((b * NHEADS + h) * 16 + c) * 16;
#pragma unroll
  for (int d = 0; d < 16; ++d) ap[d] = s[d] * r;
}

// ---------------- out[b, h*16+c, n] = sum_d attn[b,h,c,d] * v[b, h*16+d, n]
__global__ __launch_bounds__(256)
void attnv_k(const float* __restrict__ attn, const float* __restrict__ v,
             float* __restrict__ outp) {
  __shared__ float a_s[256];
  int n = blockIdx.x * 256 + threadIdx.x;
  int h = blockIdx.y, b = blockIdx.z;
  a_s[threadIdx.x] = attn[(b * NHEADS + h) * 256 + threadIdx.x];
  __syncthreads();
  float vv[16];
#pragma unroll
  for (int d = 0; d < 16; ++d) vv[d] = v[((size_t)b * NC + h * 16 + d) * NSP + n];
#pragma unroll
  for (int c = 0; c < 16; ++c) {
    float s = 0.f;
#pragma unroll
    for (int d = 0; d < 16; ++d) s += a_s[c * 16 + d] * vv[d];
    outp[((size_t)b * NC + h * 16 + c) * NSP + n] = s;
  }
}

// ---------------- final: out[b,oc,n] = proj(mid) + pos(concat[x,y]); Cout=192, 288 virtual ic
__global__ __launch_bounds__(256)
void final_k(const float* __restrict__ mid, const float* __restrict__ x,
             const float* __restrict__ y, const float* __restrict__ wproj,
             const float* __restrict__ wpos, float* __restrict__ out) {
  __shared__ float4 x_s[8 * 256];
  __shared__ float  w_s[8 * 16];
  const int tid = threadIdx.x;
  const int n0  = blockIdx.x * 1024;
  const int oc0 = blockIdx.y * 16;
  const int b   = blockIdx.z;
  float4 acc[16];
#pragma unroll
  for (int j = 0; j < 16; ++j) acc[j] = make_float4(0.f, 0.f, 0.f, 0.f);
  for (int ic0 = 0; ic0 < 288; ic0 += 8) {
    __syncthreads();
    const float* src;
    if (ic0 < 96)       src = mid + ((size_t)b * NC + ic0)         * NSP + n0;
    else if (ic0 < 192) src = x   + ((size_t)b * NC + (ic0 - 96))  * NSP + n0;
    else                src = y   + ((size_t)b * NC + (ic0 - 192)) * NSP + n0;
#pragma unroll
    for (int it = 0; it < 8; ++it) {
      int i = it * 256 + tid;
      int icl = i >> 8, c4 = i & 255;
      x_s[i] = *(const float4*)(src + (size_t)icl * NSP + (c4 << 2));
    }
    if (tid < 128) {
      int icl = tid >> 4, oc = tid & 15;
      int ic = ic0 + icl;
      w_s[icl * 16 + oc] = (ic < 96) ? wproj[(oc0 + oc) * 96 + ic]
                                     : wpos[(oc0 + oc) * 192 + (ic - 96)];
    }
    __syncthreads();
#pragma unroll
    for (int icl = 0; icl < 8; ++icl) {
      float4 xv = x_s[icl * 256 + tid];
      const float4* wp = (const float4*)&w_s[icl * 16];
#pragma unroll
      for (int g = 0; g < 4; ++g) {
        float4 wv = wp[g];
        FMA4(acc[g*4+0], wv.x, xv);
        FMA4(acc[g*4+1], wv.y, xv);
        FMA4(acc[g*4+2], wv.z, xv);
        FMA4(acc[g*4+3], wv.w, xv);
      }
    }
  }
  float* op = out + ((size_t)b * NC2 + oc0) * NSP + n0 + (tid << 2);
#pragma unroll
  for (int j = 0; j < 16; ++j)
    *(float4*)(op + (size_t)j * NSP) = acc[j];
}

extern "C" void kernel_launch(void* const* d_in, const int* in_sizes, int n_in,
                              void* d_out, int out_size, void* d_ws, size_t ws_size,
                              hipStream_t stream) {
  const float* x     = (const float*)d_in[0];
  const float* y     = (const float*)d_in[1];
  const float* wpos  = (const float*)d_in[2];
  const float* wqv   = (const float*)d_in[3];
  const float* wqvd  = (const float*)d_in[4];
  const float* wkv   = (const float*)d_in[5];
  const float* wkvd  = (const float*)d_in[6];
  const float* wproj = (const float*)d_in[7];
  const float* wfuse = (const float*)d_in[8];
  const float* bfuse = (const float*)d_in[9];
  const float* temp  = (const float*)d_in[10];
  float* out = (float*)d_out;
  float* ws  = (float*)d_ws;

  const size_t SZ = (size_t)NB * NC2 * NSP;  // 25,165,824 floats
  float* qv     = ws;                         // (B,192,N)
  float* kv     = ws + SZ;                    // (B,192,N)
  float* inv    = ws + 2 * SZ;                // 2*768 inverse norms (q then k)
  float* logits = inv + 2 * NB * NC;          // 12288
  float* attn   = logits + NB * NHEADS * 256; // 12288
  // d_out doubles as scratch: first holds qv0/kv0 (1x1 conv outputs), then v;
  // the attention output (mid) overwrites the dead q half of the qv buffer.
  float* tmp = out;
  float* v   = out;
  float* mid = qv;

  dim3 blk(256);
  conv1x1_k<<<dim3(16, 12, NB), blk, 0, stream>>>(x, wqv, tmp);
  dw3x3_k<<<dim3(64, NC2, NB), blk, 0, stream>>>(tmp, wqvd, qv);
  conv1x1_k<<<dim3(16, 12, NB), blk, 0, stream>>>(y, wkv, tmp);
  dw3x3_k<<<dim3(64, NC2, NB), blk, 0, stream>>>(tmp, wkvd, kv);
  fuse3x3_k<<<dim3(16, 6, NB), blk, 0, stream>>>(qv, kv, wfuse, bfuse, v);
  rownorm_k<<<dim3(NC, NB, 2), blk, 0, stream>>>(qv, kv, inv);
  hipMemsetAsync(logits, 0, (size_t)NB * NHEADS * 256 * sizeof(float), stream);
  qk_k<<<dim3(32, NHEADS, NB), blk, 0, stream>>>(qv, kv, logits);
  softmax_k<<<dim3(3), blk, 0, stream>>>(logits, inv, temp, attn);
  attnv_k<<<dim3(64, NHEADS, NB), blk, 0, stream>>>(attn, v, mid);
  final_k<<<dim3(16, 12, NB), blk, 0, stream>>>(mid, x, y, wproj, wpos, out);
}

// Round 2
// 795.770 us; speedup vs baseline: 2.6502x; 2.6502x over previous
//
#include <hip/hip_runtime.h>
#include <math.h>

#define NB 8
#define NSP 16384   // 128*128
#define NHEADS 6

typedef __attribute__((ext_vector_type(8))) short bf8_t;   // 8 bf16 (4 VGPR)
typedef __attribute__((ext_vector_type(4))) float f4_t;    // MFMA accumulator
typedef unsigned short u16;

#define MFMA(A,B,C) __builtin_amdgcn_mfma_f32_16x16x32_bf16((A),(B),(C),0,0,0)

__device__ __forceinline__ u16 f2b(float f) {  // fp32 -> bf16 RNE
  union { float f; unsigned u; } v; v.f = f;
  unsigned r = v.u + 0x7FFFu + ((v.u >> 16) & 1u);
  return (u16)(r >> 16);
}
__device__ __forceinline__ float b2f(u16 h) {
  union { unsigned u; float f; } v; v.u = ((unsigned)h) << 16; return v.f;
}

// ============ pack weights to bf16 (+ fuse-weight permutation to chunk-major) ============
// wfA[(kc*96 + oc)*32 + kl] = wfuse[oc][icf][tap], k = tap*192+icf, kc=tap*6+icb, icf=icb*32+kl
__global__ __launch_bounds__(256)
void pack_w_k(const float* __restrict__ wqv, const float* __restrict__ wkv,
              const float* __restrict__ wpos, const float* __restrict__ wfuse,
              u16* __restrict__ wqv_b, u16* __restrict__ wkv_b,
              u16* __restrict__ wpos_b, u16* __restrict__ wfA) {
  int i = blockIdx.x * 256 + threadIdx.x;
  if (i < 18432) { wqv_b[i] = f2b(wqv[i]); wkv_b[i] = f2b(wkv[i]); }
  if (i < 36864) wpos_b[i] = f2b(wpos[i]);
  if (i < 165888) {
    int kl = i & 31; int rest = i >> 5;
    int oc = rest % 96, kc = rest / 96;
    int tap = kc / 6, icf = (kc % 6) * 32 + kl;
    wfA[i] = f2b(wfuse[(oc * 192 + icf) * 9 + tap]);
  }
}

// ============ transpose-cast x,y: (B,96,N) fp32 -> (B*N, 96) bf16 NHWC ============
__global__ __launch_bounds__(256)
void tcast_k(const float* __restrict__ x, const float* __restrict__ y,
             u16* __restrict__ xb, u16* __restrict__ yb) {
  const float* src = blockIdx.y ? y : x;
  u16* dst = blockIdx.y ? yb : xb;
  int t = threadIdx.x;
  long n  = (long)blockIdx.x * 64 + (t & 63);
  long b  = n >> 14; long ni = n & 16383;
  int c8b = t >> 6;                 // 0..3
  for (int i = 0; i < 3; ++i) {
    int c8 = c8b + i * 4;           // 0..11
    bf8_t pk;
#pragma unroll
    for (int j = 0; j < 8; ++j)
      pk[j] = (short)f2b(src[(b * 96 + c8 * 8 + j) * NSP + ni]);
    *(bf8_t*)(dst + n * 96 + c8 * 8) = pk;
  }
}

// ============ conv1x1 MFMA: C[192 oc][64 n] = W(192x96) * X^T; NHWC bf16 out ============
__global__ __launch_bounds__(256)
void conv1x1_k(const u16* __restrict__ Bmat, const u16* __restrict__ A,
               u16* __restrict__ out) {
  int t = threadIdx.x, w = t >> 6, lane = t & 63;
  int q = lane >> 4, l15 = lane & 15;
  long n0 = (long)blockIdx.x * 64;
  f4_t acc[3][4] = {};
  const u16* Bp = Bmat + n0 * 96;
#pragma unroll
  for (int kc = 0; kc < 3; ++kc) {
    bf8_t af[3], bfr[4];
#pragma unroll
    for (int mf = 0; mf < 3; ++mf)
      af[mf] = *(const bf8_t*)(A + (w * 48 + mf * 16 + l15) * 96 + kc * 32 + q * 8);
#pragma unroll
    for (int nf = 0; nf < 4; ++nf)
      bfr[nf] = *(const bf8_t*)(Bp + (nf * 16 + l15) * 96 + kc * 32 + q * 8);
#pragma unroll
    for (int mf = 0; mf < 3; ++mf)
#pragma unroll
      for (int nf = 0; nf < 4; ++nf)
        acc[mf][nf] = MFMA(af[mf], bfr[nf], acc[mf][nf]);
  }
#pragma unroll
  for (int mf = 0; mf < 3; ++mf)
#pragma unroll
    for (int nf = 0; nf < 4; ++nf) {
      union { u16 us[4]; uint2 v; } pk;
#pragma unroll
      for (int r = 0; r < 4; ++r) pk.us[r] = f2b(acc[mf][nf][r]);
      long n = n0 + nf * 16 + l15;
      *(uint2*)(out + n * 192 + w * 48 + mf * 16 + q * 4) = pk.v;
    }
}

// ============ depthwise 3x3 NHWC: thread = channel, block = 16 px ============
__global__ __launch_bounds__(192)
void dw_k(const u16* __restrict__ in, const float* __restrict__ wd,
          u16* __restrict__ outb) {
  int c = threadIdx.x;                 // 0..191
  long g = (long)blockIdx.x * 16;      // global px
  long b = g >> 14;
  int ni0 = (int)(g & 16383);
  float wv[9];
#pragma unroll
  for (int tp = 0; tp < 9; ++tp) wv[tp] = wd[c * 9 + tp];
  const u16* base = in + (b << 14) * 192;
  for (int p = 0; p < 16; ++p) {
    int ni = ni0 + p;
    int r = ni >> 7, pw = ni & 127;
    float acc = 0.f;
#pragma unroll
    for (int dy = -1; dy <= 1; ++dy) {
      int rr = r + dy;
      if ((unsigned)rr >= 128u) continue;
#pragma unroll
      for (int dx = -1; dx <= 1; ++dx) {
        int ww = pw + dx;
        if ((unsigned)ww >= 128u) continue;
        acc += wv[(dy + 1) * 3 + (dx + 1)] * b2f(base[((long)(rr << 7) + ww) * 192 + c]);
      }
    }
    outb[(g + p) * 192 + c] = f2b(acc);
  }
}

// ============ fuse 3x3 implicit GEMM: v[96][n] = Wf(96x1728)*im2col + bias ============
// input ch j<96 -> kv[96+j], j>=96 -> qv[j]; k = tap*192 + j (chunks of 32 never cross 96)
__global__ __launch_bounds__(256)
void fuse_k(const u16* __restrict__ qv, const u16* __restrict__ kv,
            const u16* __restrict__ wfA, const float* __restrict__ bfuse,
            u16* __restrict__ vout) {
  __shared__ __align__(16) u16 AL[2][3072];   // 96 oc x 32 k, double-buffered
  int t = threadIdx.x, w = t >> 6, lane = t & 63;
  int q = lane >> 4, l15 = lane & 15;
  long n0 = (long)blockIdx.x * 128;
  long b = n0 >> 14; int nimg0 = (int)(n0 & 16383);
  const u16* qvb = qv + (b << 14) * 192;
  const u16* kvb = kv + (b << 14) * 192;

  f4_t acc[6][2];
#pragma unroll
  for (int mf = 0; mf < 6; ++mf) {
#pragma unroll
    for (int rg = 0; rg < 4; ++rg) {
      float bv = bfuse[mf * 16 + q * 4 + rg];
      acc[mf][0][rg] = bv; acc[mf][1][rg] = bv;
    }
  }
  // per-lane pixel coords for the 2 n-frags
  int ni_[2], r_[2], pw_[2];
#pragma unroll
  for (int nf = 0; nf < 2; ++nf) {
    ni_[nf] = nimg0 + w * 32 + nf * 16 + l15;
    r_[nf] = ni_[nf] >> 7; pw_[nf] = ni_[nf] & 127;
  }
  // stage chunk 0
  for (int i = t; i < 384; i += 256)
    *(f4_t*)((char*)AL[0] + i * 16) = *(const f4_t*)((const char*)wfA + i * 16);
  __syncthreads();

  for (int kc = 0; kc < 54; ++kc) {
    int cur = kc & 1;
    if (kc < 53) {
      const char* srcw = (const char*)(wfA + (kc + 1) * 3072);
      for (int i = t; i < 384; i += 256)
        *(f4_t*)((char*)AL[cur ^ 1] + i * 16) = *(const f4_t*)(srcw + i * 16);
    }
    int tap = kc / 6, icfb = (kc % 6) * 32;
    int dy = tap / 3 - 1, dx = tap % 3 - 1;
    const u16* src; int chb;
    if (icfb < 96) { src = kvb; chb = 96 + icfb; }
    else           { src = qvb; chb = icfb; }
    bf8_t bfr[2];
#pragma unroll
    for (int nf = 0; nf < 2; ++nf) {
      bf8_t v = {0,0,0,0,0,0,0,0};
      int rr = r_[nf] + dy, cc = pw_[nf] + dx;
      if ((unsigned)rr < 128u && (unsigned)cc < 128u)
        v = *(const bf8_t*)(src + ((long)ni_[nf] + dy * 128 + dx) * 192 + chb + q * 8);
      bfr[nf] = v;
    }
    bf8_t af[6];
#pragma unroll
    for (int mf = 0; mf < 6; ++mf)
      af[mf] = *(const bf8_t*)(&AL[cur][(mf * 16 + l15) * 32 + q * 8]);
#pragma unroll
    for (int mf = 0; mf < 6; ++mf) {
      acc[mf][0] = MFMA(af[mf], bfr[0], acc[mf][0]);
      acc[mf][1] = MFMA(af[mf], bfr[1], acc[mf][1]);
    }
    __syncthreads();
  }
#pragma unroll
  for (int mf = 0; mf < 6; ++mf)
#pragma unroll
    for (int nf = 0; nf < 2; ++nf) {
      union { u16 us[4]; uint2 v; } pk;
#pragma unroll
      for (int rg = 0; rg < 4; ++rg) pk.us[rg] = f2b(acc[mf][nf][rg]);
      long n = n0 + w * 32 + nf * 16 + l15;
      *(uint2*)(vout + n * 96 + mf * 16 + q * 4) = pk.v;
    }
}

// ============ per-channel L2 norms over spatial (lo 96 ch of qv/kv) ============
__global__ __launch_bounds__(256)
void rnorm_k(const u16* __restrict__ qv, const u16* __restrict__ kv,
             float* __restrict__ inv) {
  int c8 = blockIdx.x, b = blockIdx.y, z = blockIdx.z;
  const u16* src = (z ? kv : qv) + ((long)b << 14) * 192 + c8 * 8;
  float ss[8] = {};
  for (int n = threadIdx.x; n < NSP; n += 256) {
    bf8_t v = *(const bf8_t*)(src + (long)n * 192);
#pragma unroll
    for (int j = 0; j < 8; ++j) { float f = b2f((u16)v[j]); ss[j] += f * f; }
  }
#pragma unroll
  for (int off = 32; off; off >>= 1)
#pragma unroll
    for (int j = 0; j < 8; ++j) ss[j] += __shfl_down(ss[j], off);
  __shared__ float red[4][8];
  int lane = threadIdx.x & 63, wv = threadIdx.x >> 6;
  if (!lane)
#pragma unroll
    for (int j = 0; j < 8; ++j) red[wv][j] = ss[j];
  __syncthreads();
  if (threadIdx.x < 8) {
    int j = threadIdx.x;
    float tot = red[0][j] + red[1][j] + red[2][j] + red[3][j];
    inv[(z * NB + b) * 96 + c8 * 8 + j] = 1.f / fmaxf(sqrtf(tot), 1e-12f);
  }
}

// ============ QK^T: logits[b,h,c,d] = sum_n q[n][h16+c] k[n][h16+d] (raw) ============
__global__ __launch_bounds__(256)
void qk_k(const u16* __restrict__ qv, const u16* __restrict__ kv,
          float* __restrict__ logits) {
  int s = blockIdx.x, h = blockIdx.y, b = blockIdx.z;
  int t = threadIdx.x, c = t >> 4, d = t & 15;
  __shared__ u16 Qs[64 * 16], Ks[64 * 16];
  long base = (((long)b << 14) + s * 2048) * 192 + h * 16;
  float acc = 0.f;
  int p = t >> 2, c4 = (t & 3) * 4;
  for (int it = 0; it < 32; ++it) {
    __syncthreads();
    long a = base + (long)(it * 64 + p) * 192 + c4;
    *(uint2*)(&Qs[p * 16 + c4]) = *(const uint2*)(qv + a);
    *(uint2*)(&Ks[p * 16 + c4]) = *(const uint2*)(kv + a);
    __syncthreads();
#pragma unroll 8
    for (int pp = 0; pp < 64; ++pp)
      acc += b2f(Qs[pp * 16 + c]) * b2f(Ks[pp * 16 + d]);
  }
  atomicAdd(&logits[((b * NHEADS + h) * 16 + c) * 16 + d], acc);
}

// ============ softmax with norm + temperature scaling ============
__global__ __launch_bounds__(256)
void softmax_k(const float* __restrict__ logits, const float* __restrict__ inv,
               const float* __restrict__ temp, float* __restrict__ attn) {
  int t0 = blockIdx.x * 256 + threadIdx.x;
  if (t0 >= NB * 96) return;
  int b = t0 / 96, c96 = t0 % 96;
  int h = c96 >> 4, c = c96 & 15;
  float iq = inv[b * 96 + c96];
  float tp = temp[h];
  const float* lp = logits + ((b * NHEADS + h) * 16 + c) * 16;
  const float* ik = inv + NB * 96 + b * 96 + h * 16;
  float s[16], mx = -3.4e38f;
#pragma unroll
  for (int d = 0; d < 16; ++d) {
    float l = lp[d] * iq * ik[d] * tp;
    s[d] = l; mx = fmaxf(mx, l);
  }
  float sum = 0.f;
#pragma unroll
  for (int d = 0; d < 16; ++d) { s[d] = __expf(s[d] - mx); sum += s[d]; }
  float rr = 1.f / sum;
  float* ap = attn + ((b * NHEADS + h) * 16 + c) * 16;
#pragma unroll
  for (int d = 0; d < 16; ++d) ap[d] = s[d] * rr;
}

// ============ W'[b] = Wproj * blockdiag(attn_b): (192 x 96) bf16 per batch ============
__global__ __launch_bounds__(256)
void wattn_k(const float* __restrict__ wproj, const float* __restrict__ attn,
             u16* __restrict__ Wp) {
  int b = blockIdx.x, t = threadIdx.x;
  __shared__ float at[1536];
  for (int i = t; i < 1536; i += 256) at[i] = attn[b * 1536 + i];
  __syncthreads();
  for (int i = t; i < 192 * 96; i += 256) {
    int oc = i / 96, e = i % 96;
    int h = e >> 4, d = e & 15;
    float s = 0.f;
#pragma unroll
    for (int c = 0; c < 16; ++c)
      s += wproj[oc * 96 + h * 16 + c] * at[(h * 16 + c) * 16 + d];
    Wp[(long)b * 18432 + i] = f2b(s);
  }
}

// ============ final: out = [W'_b | Wpos] * [v; x; y]; NCHW fp32 out ============
__global__ __launch_bounds__(256)
void final_k(const u16* __restrict__ Wp, const u16* __restrict__ wpos_b,
             const u16* __restrict__ v, const u16* __restrict__ xb,
             const u16* __restrict__ yb, float* __restrict__ out) {
  int t = threadIdx.x, w = t >> 6, lane = t & 63;
  int q = lane >> 4, l15 = lane & 15;
  long n0 = (long)blockIdx.x * 64;
  long b = n0 >> 14; int ni0 = (int)(n0 & 16383);
  f4_t acc[3][4] = {};
  const u16* Ab0 = Wp + b * 18432;
#pragma unroll
  for (int kc = 0; kc < 9; ++kc) {
    const u16 *Asrc, *Bsrc; int astr, koff;
    if (kc < 3)      { Asrc = Ab0;    astr = 96;  koff = kc * 32;            Bsrc = v  + n0 * 96 + kc * 32; }
    else if (kc < 6) { Asrc = wpos_b; astr = 192; koff = (kc - 3) * 32;      Bsrc = xb + n0 * 96 + (kc - 3) * 32; }
    else             { Asrc = wpos_b; astr = 192; koff = 96 + (kc - 6) * 32; Bsrc = yb + n0 * 96 + (kc - 6) * 32; }
    bf8_t af[3], bfr[4];
#pragma unroll
    for (int mf = 0; mf < 3; ++mf)
      af[mf] = *(const bf8_t*)(Asrc + (w * 48 + mf * 16 + l15) * astr + koff + q * 8);
#pragma unroll
    for (int nf = 0; nf < 4; ++nf)
      bfr[nf] = *(const bf8_t*)(Bsrc + (long)(nf * 16 + l15) * 96 + q * 8);
#pragma unroll
    for (int mf = 0; mf < 3; ++mf)
#pragma unroll
      for (int nf = 0; nf < 4; ++nf)
        acc[mf][nf] = MFMA(af[mf], bfr[nf], acc[mf][nf]);
  }
  // NCHW fp32 stores: per (oc), 16 lanes write 64B contiguous, 64B-aligned
#pragma unroll
  for (int mf = 0; mf < 3; ++mf)
#pragma unroll
    for (int nf = 0; nf < 4; ++nf)
#pragma unroll
      for (int rg = 0; rg < 4; ++rg) {
        int oc = w * 48 + mf * 16 + q * 4 + rg;
        out[(b * 192 + oc) * (long)NSP + ni0 + nf * 16 + l15] = acc[mf][nf][rg];
      }
}

extern "C" void kernel_launch(void* const* d_in, const int* in_sizes, int n_in,
                              void* d_out, int out_size, void* d_ws, size_t ws_size,
                              hipStream_t stream) {
  const float* x     = (const float*)d_in[0];
  const float* y     = (const float*)d_in[1];
  const float* wpos  = (const float*)d_in[2];
  const float* wqv   = (const float*)d_in[3];
  const float* wqvd  = (const float*)d_in[4];
  const float* wkv   = (const float*)d_in[5];
  const float* wkvd  = (const float*)d_in[6];
  const float* wproj = (const float*)d_in[7];
  const float* wfuse = (const float*)d_in[8];
  const float* bfuse = (const float*)d_in[9];
  const float* temp  = (const float*)d_in[10];
  float* out = (float*)d_out;
  char*  ws  = (char*)d_ws;

  // ws layout (bytes)
  u16*   xb     = (u16*)(ws);                          // 25,165,824
  u16*   yb     = (u16*)(ws + 25165824);               // 25,165,824
  u16*   qv     = (u16*)(ws + 50331648);               // 50,331,648
  u16*   kv     = (u16*)(ws + 100663296);              // 50,331,648
  u16*   v      = (u16*)(ws + 150994944);              // 25,165,824
  u16*   wqv_b  = (u16*)(ws + 176160768);              // 36,864
  u16*   wkv_b  = (u16*)(ws + 176197632);              // 36,864
  u16*   wpos_b = (u16*)(ws + 176234496);              // 73,728
  u16*   wfA    = (u16*)(ws + 176308224);              // 331,776
  u16*   Wp     = (u16*)(ws + 176640000);              // 294,912
  float* inv    = (float*)(ws + 176934912);            // 6,144
  float* logits = (float*)(ws + 176941056);            // 49,152
  float* attn   = (float*)(ws + 176990208);            // 49,152

  // d_out doubles as bf16 scratch for the two 1x1-conv outputs (dead after dw)
  u16* qv0 = (u16*)d_out;
  u16* kv0 = (u16*)d_out + (size_t)NB * NSP * 192;

  dim3 blk(256);
  pack_w_k<<<648, blk, 0, stream>>>(wqv, wkv, wpos, wfuse, wqv_b, wkv_b, wpos_b, wfA);
  tcast_k<<<dim3(2048, 2), blk, 0, stream>>>(x, y, xb, yb);
  conv1x1_k<<<2048, blk, 0, stream>>>(xb, wqv_b, qv0);
  conv1x1_k<<<2048, blk, 0, stream>>>(yb, wkv_b, kv0);
  dw_k<<<8192, dim3(192), 0, stream>>>(qv0, wqvd, qv);
  dw_k<<<8192, dim3(192), 0, stream>>>(kv0, wkvd, kv);
  fuse_k<<<1024, blk, 0, stream>>>(qv, kv, wfA, bfuse, v);
  rnorm_k<<<dim3(12, NB, 2), blk, 0, stream>>>(qv, kv, inv);
  hipMemsetAsync(logits, 0, (size_t)NB * NHEADS * 256 * sizeof(float), stream);
  qk_k<<<dim3(8, NHEADS, NB), blk, 0, stream>>>(qv, kv, logits);
  softmax_k<<<3, blk, 0, stream>>>(logits, inv, temp, attn);
  wattn_k<<<NB, blk, 0, stream>>>(wproj, attn, Wp);
  final_k<<<2048, blk, 0, stream>>>(Wp, wpos_b, v, xb, yb, out);
}

// Round 3
// 626.243 us; speedup vs baseline: 3.3677x; 1.2707x over previous
//
#include <hip/hip_runtime.h>
#include <math.h>

#define NB 8
#define NSP 16384   // 128*128
#define NHEADS 6

typedef __attribute__((ext_vector_type(8))) short bf8_t;   // 8 bf16 (4 VGPR)
typedef __attribute__((ext_vector_type(4))) float f4_t;    // MFMA accumulator
typedef unsigned short u16;

#define MFMA(A,B,C) __builtin_amdgcn_mfma_f32_16x16x32_bf16((A),(B),(C),0,0,0)

__device__ __forceinline__ u16 f2b(float f) {  // fp32 -> bf16 RNE
  union { float f; unsigned u; } v; v.f = f;
  unsigned r = v.u + 0x7FFFu + ((v.u >> 16) & 1u);
  return (u16)(r >> 16);
}
__device__ __forceinline__ float b2f(u16 h) {
  union { unsigned u; float f; } v; v.u = ((unsigned)h) << 16; return v.f;
}

// ============ pack weights to bf16 (+ fuse-weight permutation to chunk-major) ============
__global__ __launch_bounds__(256)
void pack_w_k(const float* __restrict__ wqv, const float* __restrict__ wkv,
              const float* __restrict__ wpos, const float* __restrict__ wfuse,
              u16* __restrict__ wqv_b, u16* __restrict__ wkv_b,
              u16* __restrict__ wpos_b, u16* __restrict__ wfA) {
  int i = blockIdx.x * 256 + threadIdx.x;
  if (i < 18432) { wqv_b[i] = f2b(wqv[i]); wkv_b[i] = f2b(wkv[i]); }
  if (i < 36864) wpos_b[i] = f2b(wpos[i]);
  if (i < 165888) {
    int kl = i & 31; int rest = i >> 5;
    int oc = rest % 96, kc = rest / 96;
    int tap = kc / 6, icf = (kc % 6) * 32 + kl;
    wfA[i] = f2b(wfuse[(oc * 192 + icf) * 9 + tap]);
  }
}

// ============ transpose-cast x,y: (B,96,N) fp32 -> (B*N, 96) bf16 NHWC ============
__global__ __launch_bounds__(256)
void tcast_k(const float* __restrict__ x, const float* __restrict__ y,
             u16* __restrict__ xb, u16* __restrict__ yb) {
  const float* src = blockIdx.y ? y : x;
  u16* dst = blockIdx.y ? yb : xb;
  int t = threadIdx.x;
  long n  = (long)blockIdx.x * 64 + (t & 63);
  long b  = n >> 14; long ni = n & 16383;
  int c8b = t >> 6;                 // 0..3
  for (int i = 0; i < 3; ++i) {
    int c8 = c8b + i * 4;           // 0..11
    bf8_t pk;
#pragma unroll
    for (int j = 0; j < 8; ++j)
      pk[j] = (short)f2b(src[(b * 96 + c8 * 8 + j) * NSP + ni]);
    *(bf8_t*)(dst + n * 96 + c8 * 8) = pk;
  }
}

// ============ conv1x1 MFMA: C[192 oc][64 n] = W(192x96) * X^T; NHWC bf16 out ============
__global__ __launch_bounds__(256)
void conv1x1_k(const u16* __restrict__ Bmat, const u16* __restrict__ A,
               u16* __restrict__ out) {
  int t = threadIdx.x, w = t >> 6, lane = t & 63;
  int q = lane >> 4, l15 = lane & 15;
  long n0 = (long)blockIdx.x * 64;
  f4_t acc[3][4] = {};
  const u16* Bp = Bmat + n0 * 96;
#pragma unroll
  for (int kc = 0; kc < 3; ++kc) {
    bf8_t af[3], bfr[4];
#pragma unroll
    for (int mf = 0; mf < 3; ++mf)
      af[mf] = *(const bf8_t*)(A + (w * 48 + mf * 16 + l15) * 96 + kc * 32 + q * 8);
#pragma unroll
    for (int nf = 0; nf < 4; ++nf)
      bfr[nf] = *(const bf8_t*)(Bp + (nf * 16 + l15) * 96 + kc * 32 + q * 8);
#pragma unroll
    for (int mf = 0; mf < 3; ++mf)
#pragma unroll
      for (int nf = 0; nf < 4; ++nf)
        acc[mf][nf] = MFMA(af[mf], bfr[nf], acc[mf][nf]);
  }
#pragma unroll
  for (int mf = 0; mf < 3; ++mf)
#pragma unroll
    for (int nf = 0; nf < 4; ++nf) {
      union { u16 us[4]; uint2 v; } pk;
#pragma unroll
      for (int r = 0; r < 4; ++r) pk.us[r] = f2b(acc[mf][nf][r]);
      long n = n0 + nf * 16 + l15;
      *(uint2*)(out + n * 192 + w * 48 + mf * 16 + q * 4) = pk.v;
    }
}

// ============ depthwise 3x3 NHWC, vectorized: thread = 8 ch x 4 px ============
// grid.x: 4096 = (B*128 rows) * 4 tiles of 32px; grid.y: 0=qv path, 1=kv path
__global__ __launch_bounds__(192)
void dw_k(const u16* __restrict__ qv0, const u16* __restrict__ kv0,
          const float* __restrict__ wqvd, const float* __restrict__ wkvd,
          u16* __restrict__ qvo, u16* __restrict__ kvo) {
  __shared__ float wt_s[9 * 192];
  int t = threadIdx.x;
  int sel = blockIdx.y;
  const u16* inb  = sel ? kv0 : qv0;
  u16* outb       = sel ? kvo : qvo;
  const float* wd = sel ? wkvd : wqvd;
  // stage weights transposed: wt_s[tap*192 + c]
  for (int i = t; i < 1728; i += 192) {
    int c = i / 9, tp = i - c * 9;
    wt_s[tp * 192 + c] = wd[i];
  }
  __syncthreads();
  int bx = blockIdx.x;
  int tile = bx & 3, rowid = bx >> 2;
  long b = rowid >> 7; int r = rowid & 127;
  int g = t % 24, ps = t / 24;          // channel-group 0..23, pixel-slot 0..7
  int wcol = tile * 32 + ps * 4;        // first output col
  float acc[4][8] = {};
#pragma unroll
  for (int dy = -1; dy <= 1; ++dy) {
    int rr = r + dy;
    bool vrow = (unsigned)rr < 128u;
    float xv[6][8];
#pragma unroll
    for (int j2 = 0; j2 < 6; ++j2) {
      int col = wcol - 1 + j2;
      uint4 cv = make_uint4(0u, 0u, 0u, 0u);
      if (vrow && (unsigned)col < 128u)
        cv = *(const uint4*)(inb + ((b << 14) + ((long)rr << 7) + col) * 192 + g * 8);
      const unsigned* cu = (const unsigned*)&cv;
#pragma unroll
      for (int k = 0; k < 4; ++k) {
        union { unsigned u; float f; } lo, hi;
        lo.u = cu[k] << 16; hi.u = cu[k] & 0xFFFF0000u;
        xv[j2][2 * k] = lo.f; xv[j2][2 * k + 1] = hi.f;
      }
    }
#pragma unroll
    for (int dx = 0; dx < 3; ++dx) {
      const float* wp = &wt_s[((dy + 1) * 3 + dx) * 192 + g * 8];
      float4 wa = *(const float4*)wp;
      float4 wb = *(const float4*)(wp + 4);
      float w8[8] = {wa.x, wa.y, wa.z, wa.w, wb.x, wb.y, wb.z, wb.w};
#pragma unroll
      for (int j = 0; j < 4; ++j)
#pragma unroll
        for (int ch = 0; ch < 8; ++ch)
          acc[j][ch] += w8[ch] * xv[j + dx][ch];
    }
  }
#pragma unroll
  for (int j = 0; j < 4; ++j) {
    union { u16 us[8]; uint4 v; } pk;
#pragma unroll
    for (int ch = 0; ch < 8; ++ch) pk.us[ch] = f2b(acc[j][ch]);
    *(uint4*)(outb + ((b << 14) + ((long)r << 7) + wcol + j) * 192 + g * 8) = pk.v;
  }
}

// ============ fuse 3x3 implicit GEMM: v[96][n] = Wf(96x1728)*im2col + bias ============
__global__ __launch_bounds__(256)
void fuse_k(const u16* __restrict__ qv, const u16* __restrict__ kv,
            const u16* __restrict__ wfA, const float* __restrict__ bfuse,
            u16* __restrict__ vout) {
  __shared__ __align__(16) u16 AL[2][3072];   // 96 oc x 32 k, double-buffered
  int t = threadIdx.x, w = t >> 6, lane = t & 63;
  int q = lane >> 4, l15 = lane & 15;
  long n0 = (long)blockIdx.x * 128;
  long b = n0 >> 14; int nimg0 = (int)(n0 & 16383);
  const u16* qvb = qv + (b << 14) * 192;
  const u16* kvb = kv + (b << 14) * 192;

  f4_t acc[6][2];
#pragma unroll
  for (int mf = 0; mf < 6; ++mf) {
#pragma unroll
    for (int rg = 0; rg < 4; ++rg) {
      float bv = bfuse[mf * 16 + q * 4 + rg];
      acc[mf][0][rg] = bv; acc[mf][1][rg] = bv;
    }
  }
  int ni_[2], r_[2], pw_[2];
#pragma unroll
  for (int nf = 0; nf < 2; ++nf) {
    ni_[nf] = nimg0 + w * 32 + nf * 16 + l15;
    r_[nf] = ni_[nf] >> 7; pw_[nf] = ni_[nf] & 127;
  }
  for (int i = t; i < 384; i += 256)
    *(f4_t*)((char*)AL[0] + i * 16) = *(const f4_t*)((const char*)wfA + i * 16);
  __syncthreads();

  for (int kc = 0; kc < 54; ++kc) {
    int cur = kc & 1;
    if (kc < 53) {
      const char* srcw = (const char*)(wfA + (kc + 1) * 3072);
      for (int i = t; i < 384; i += 256)
        *(f4_t*)((char*)AL[cur ^ 1] + i * 16) = *(const f4_t*)(srcw + i * 16);
    }
    int tap = kc / 6, icfb = (kc % 6) * 32;
    int dy = tap / 3 - 1, dx = tap % 3 - 1;
    const u16* src; int chb;
    if (icfb < 96) { src = kvb; chb = 96 + icfb; }
    else           { src = qvb; chb = icfb; }
    bf8_t bfr[2];
#pragma unroll
    for (int nf = 0; nf < 2; ++nf) {
      bf8_t v = {0,0,0,0,0,0,0,0};
      int rr = r_[nf] + dy, cc = pw_[nf] + dx;
      if ((unsigned)rr < 128u && (unsigned)cc < 128u)
        v = *(const bf8_t*)(src + ((long)ni_[nf] + dy * 128 + dx) * 192 + chb + q * 8);
      bfr[nf] = v;
    }
    bf8_t af[6];
#pragma unroll
    for (int mf = 0; mf < 6; ++mf)
      af[mf] = *(const bf8_t*)(&AL[cur][(mf * 16 + l15) * 32 + q * 8]);
#pragma unroll
    for (int mf = 0; mf < 6; ++mf) {
      acc[mf][0] = MFMA(af[mf], bfr[0], acc[mf][0]);
      acc[mf][1] = MFMA(af[mf], bfr[1], acc[mf][1]);
    }
    __syncthreads();
  }
#pragma unroll
  for (int mf = 0; mf < 6; ++mf)
#pragma unroll
    for (int nf = 0; nf < 2; ++nf) {
      union { u16 us[4]; uint2 v; } pk;
#pragma unroll
      for (int rg = 0; rg < 4; ++rg) pk.us[rg] = f2b(acc[mf][nf][rg]);
      long n = n0 + w * 32 + nf * 16 + l15;
      *(uint2*)(vout + n * 96 + mf * 16 + q * 4) = pk.v;
    }
}

// ============ per-channel L2 norms over spatial (lo 96 ch of qv/kv) ============
__global__ __launch_bounds__(256)
void rnorm_k(const u16* __restrict__ qv, const u16* __restrict__ kv,
             float* __restrict__ inv) {
  int c8 = blockIdx.x, b = blockIdx.y, z = blockIdx.z;
  const u16* src = (z ? kv : qv) + ((long)b << 14) * 192 + c8 * 8;
  float ss[8] = {};
  for (int n = threadIdx.x; n < NSP; n += 256) {
    bf8_t v = *(const bf8_t*)(src + (long)n * 192);
#pragma unroll
    for (int j = 0; j < 8; ++j) { float f = b2f((u16)v[j]); ss[j] += f * f; }
  }
#pragma unroll
  for (int off = 32; off; off >>= 1)
#pragma unroll
    for (int j = 0; j < 8; ++j) ss[j] += __shfl_down(ss[j], off);
  __shared__ float red[4][8];
  int lane = threadIdx.x & 63, wv = threadIdx.x >> 6;
  if (!lane)
#pragma unroll
    for (int j = 0; j < 8; ++j) red[wv][j] = ss[j];
  __syncthreads();
  if (threadIdx.x < 8) {
    int j = threadIdx.x;
    float tot = red[0][j] + red[1][j] + red[2][j] + red[3][j];
    inv[(z * NB + b) * 96 + c8 * 8 + j] = 1.f / fmaxf(sqrtf(tot), 1e-12f);
  }
}

// ============ QK^T: logits[b,h,c,d] = sum_n q[n][h16+c] k[n][h16+d] (raw) ============
__global__ __launch_bounds__(256)
void qk_k(const u16* __restrict__ qv, const u16* __restrict__ kv,
          float* __restrict__ logits) {
  int s = blockIdx.x, h = blockIdx.y, b = blockIdx.z;
  int t = threadIdx.x, c = t >> 4, d = t & 15;
  __shared__ u16 Qs[64 * 16], Ks[64 * 16];
  long base = (((long)b << 14) + s * 2048) * 192 + h * 16;
  float acc = 0.f;
  int p = t >> 2, c4 = (t & 3) * 4;
  for (int it = 0; it < 32; ++it) {
    __syncthreads();
    long a = base + (long)(it * 64 + p) * 192 + c4;
    *(uint2*)(&Qs[p * 16 + c4]) = *(const uint2*)(qv + a);
    *(uint2*)(&Ks[p * 16 + c4]) = *(const uint2*)(kv + a);
    __syncthreads();
#pragma unroll 8
    for (int pp = 0; pp < 64; ++pp)
      acc += b2f(Qs[pp * 16 + c]) * b2f(Ks[pp * 16 + d]);
  }
  atomicAdd(&logits[((b * NHEADS + h) * 16 + c) * 16 + d], acc);
}

// ============ softmax with norm + temperature scaling ============
__global__ __launch_bounds__(256)
void softmax_k(const float* __restrict__ logits, const float* __restrict__ inv,
               const float* __restrict__ temp, float* __restrict__ attn) {
  int t0 = blockIdx.x * 256 + threadIdx.x;
  if (t0 >= NB * 96) return;
  int b = t0 / 96, c96 = t0 % 96;
  int h = c96 >> 4, c = c96 & 15;
  float iq = inv[b * 96 + c96];
  float tp = temp[h];
  const float* lp = logits + ((b * NHEADS + h) * 16 + c) * 16;
  const float* ik = inv + NB * 96 + b * 96 + h * 16;
  float s[16], mx = -3.4e38f;
#pragma unroll
  for (int d = 0; d < 16; ++d) {
    float l = lp[d] * iq * ik[d] * tp;
    s[d] = l; mx = fmaxf(mx, l);
  }
  float sum = 0.f;
#pragma unroll
  for (int d = 0; d < 16; ++d) { s[d] = __expf(s[d] - mx); sum += s[d]; }
  float rr = 1.f / sum;
  float* ap = attn + ((b * NHEADS + h) * 16 + c) * 16;
#pragma unroll
  for (int d = 0; d < 16; ++d) ap[d] = s[d] * rr;
}

// ============ W'[b] = Wproj * blockdiag(attn_b): (192 x 96) bf16 per batch ============
__global__ __launch_bounds__(256)
void wattn_k(const float* __restrict__ wproj, const float* __restrict__ attn,
             u16* __restrict__ Wp) {
  int b = blockIdx.x, t = threadIdx.x;
  __shared__ float at[1536];
  for (int i = t; i < 1536; i += 256) at[i] = attn[b * 1536 + i];
  __syncthreads();
  for (int i = t; i < 192 * 96; i += 256) {
    int oc = i / 96, e = i % 96;
    int h = e >> 4, d = e & 15;
    float s = 0.f;
#pragma unroll
    for (int c = 0; c < 16; ++c)
      s += wproj[oc * 96 + h * 16 + c] * at[(h * 16 + c) * 16 + d];
    Wp[(long)b * 18432 + i] = f2b(s);
  }
}

// ============ final: out = [W'_b | Wpos] * [v; x; y]; NCHW fp32 out ============
__global__ __launch_bounds__(256)
void final_k(const u16* __restrict__ Wp, const u16* __restrict__ wpos_b,
             const u16* __restrict__ v, const u16* __restrict__ xb,
             const u16* __restrict__ yb, float* __restrict__ out) {
  int t = threadIdx.x, w = t >> 6, lane = t & 63;
  int q = lane >> 4, l15 = lane & 15;
  long n0 = (long)blockIdx.x * 64;
  long b = n0 >> 14; int ni0 = (int)(n0 & 16383);
  f4_t acc[3][4] = {};
  const u16* Ab0 = Wp + b * 18432;
#pragma unroll
  for (int kc = 0; kc < 9; ++kc) {
    const u16 *Asrc, *Bsrc; int astr, koff;
    if (kc < 3)      { Asrc = Ab0;    astr = 96;  koff = kc * 32;            Bsrc = v  + n0 * 96 + kc * 32; }
    else if (kc < 6) { Asrc = wpos_b; astr = 192; koff = (kc - 3) * 32;      Bsrc = xb + n0 * 96 + (kc - 3) * 32; }
    else             { Asrc = wpos_b; astr = 192; koff = 96 + (kc - 6) * 32; Bsrc = yb + n0 * 96 + (kc - 6) * 32; }
    bf8_t af[3], bfr[4];
#pragma unroll
    for (int mf = 0; mf < 3; ++mf)
      af[mf] = *(const bf8_t*)(Asrc + (w * 48 + mf * 16 + l15) * astr + koff + q * 8);
#pragma unroll
    for (int nf = 0; nf < 4; ++nf)
      bfr[nf] = *(const bf8_t*)(Bsrc + (long)(nf * 16 + l15) * 96 + q * 8);
#pragma unroll
    for (int mf = 0; mf < 3; ++mf)
#pragma unroll
      for (int nf = 0; nf < 4; ++nf)
        acc[mf][nf] = MFMA(af[mf], bfr[nf], acc[mf][nf]);
  }
#pragma unroll
  for (int mf = 0; mf < 3; ++mf)
#pragma unroll
    for (int nf = 0; nf < 4; ++nf)
#pragma unroll
      for (int rg = 0; rg < 4; ++rg) {
        int oc = w * 48 + mf * 16 + q * 4 + rg;
        out[(b * 192 + oc) * (long)NSP + ni0 + nf * 16 + l15] = acc[mf][nf][rg];
      }
}

extern "C" void kernel_launch(void* const* d_in, const int* in_sizes, int n_in,
                              void* d_out, int out_size, void* d_ws, size_t ws_size,
                              hipStream_t stream) {
  const float* x     = (const float*)d_in[0];
  const float* y     = (const float*)d_in[1];
  const float* wpos  = (const float*)d_in[2];
  const float* wqv   = (const float*)d_in[3];
  const float* wqvd  = (const float*)d_in[4];
  const float* wkv   = (const float*)d_in[5];
  const float* wkvd  = (const float*)d_in[6];
  const float* wproj = (const float*)d_in[7];
  const float* wfuse = (const float*)d_in[8];
  const float* bfuse = (const float*)d_in[9];
  const float* temp  = (const float*)d_in[10];
  float* out = (float*)d_out;
  char*  ws  = (char*)d_ws;

  u16*   xb     = (u16*)(ws);
  u16*   yb     = (u16*)(ws + 25165824);
  u16*   qv     = (u16*)(ws + 50331648);
  u16*   kv     = (u16*)(ws + 100663296);
  u16*   v      = (u16*)(ws + 150994944);
  u16*   wqv_b  = (u16*)(ws + 176160768);
  u16*   wkv_b  = (u16*)(ws + 176197632);
  u16*   wpos_b = (u16*)(ws + 176234496);
  u16*   wfA    = (u16*)(ws + 176308224);
  u16*   Wp     = (u16*)(ws + 176640000);
  float* inv    = (float*)(ws + 176934912);
  float* logits = (float*)(ws + 176941056);
  float* attn   = (float*)(ws + 176990208);

  // d_out doubles as bf16 scratch for the two 1x1-conv outputs (dead after dw)
  u16* qv0 = (u16*)d_out;
  u16* kv0 = (u16*)d_out + (size_t)NB * NSP * 192;

  dim3 blk(256);
  pack_w_k<<<648, blk, 0, stream>>>(wqv, wkv, wpos, wfuse, wqv_b, wkv_b, wpos_b, wfA);
  tcast_k<<<dim3(2048, 2), blk, 0, stream>>>(x, y, xb, yb);
  conv1x1_k<<<2048, blk, 0, stream>>>(xb, wqv_b, qv0);
  conv1x1_k<<<2048, blk, 0, stream>>>(yb, wkv_b, kv0);
  dw_k<<<dim3(4096, 2), dim3(192), 0, stream>>>(qv0, kv0, wqvd, wkvd, qv, kv);
  fuse_k<<<1024, blk, 0, stream>>>(qv, kv, wfA, bfuse, v);
  rnorm_k<<<dim3(12, NB, 2), blk, 0, stream>>>(qv, kv, inv);
  hipMemsetAsync(logits, 0, (size_t)NB * NHEADS * 256 * sizeof(float), stream);
  qk_k<<<dim3(8, NHEADS, NB), blk, 0, stream>>>(qv, kv, logits);
  softmax_k<<<3, blk, 0, stream>>>(logits, inv, temp, attn);
  wattn_k<<<NB, blk, 0, stream>>>(wproj, attn, Wp);
  final_k<<<2048, blk, 0, stream>>>(Wp, wpos_b, v, xb, yb, out);
}